// Round 14
// baseline (191.169 us; speedup 1.0000x reference)
//
#include <hip/hip_runtime.h>
#include <stdint.h>

typedef int   v4i __attribute__((ext_vector_type(4)));
typedef float v4f __attribute__((ext_vector_type(4)));

// xt layout: [n][hp=58][wp=66][ci=128] int8, zero-padded (hp-1,wp-1 are src coords)
#define XT_H_STRIDE (66*128)          // 8448
#define XT_N_STRIDE (58*66*128)       // 489984
#define XT_BYTES    (32*58*66*128)    // 15,679,488
#define WQ_BYTES    (256*1152)        // 294,912

__device__ __forceinline__ void gload16(const void* g, void* l) {
  __builtin_amdgcn_global_load_lds(
      (const __attribute__((address_space(1))) void*)g,
      (__attribute__((address_space(3))) void*)l, 16, 0, 0);
}

// ---------------- x transform: fp32 NCHW -> int8 [n][hp][wp][ci] ----------------
// Coalesced both sides via LDS transpose. Unchanged (proven, HBM roofline).
__global__ __launch_bounds__(256) void xform_x(const float* __restrict__ x,
                                               char* __restrict__ xt) {
  __shared__ int LB[56 * 33];          // [w][32 ci-dwords + 1 pad]
  int bid = blockIdx.x;                // 32*58
  int n  = bid / 58;
  int hp = bid - n * 58;
  int t  = threadIdx.x;
  int srch = hp - 1;
  bool rowok = (srch >= 0) && (srch < 56);
  char* dstrow = xt + (size_t)n * XT_N_STRIDE + (size_t)hp * XT_H_STRIDE;

  if (rowok) {
    const float* rb = x + ((size_t)(n * 128) * 56 + srch) * 56;   // + ci*3136 + w
#pragma unroll
    for (int u0 = 0; u0 < 2; ++u0) {
      int u  = t + u0 * 256;
      int wb = u & 15;
      int cb = u >> 4;
      int w0 = wb * 4, ci0 = cb * 4;
      if (w0 < 56) {
        int dw[4] = {0, 0, 0, 0};
#pragma unroll
        for (int i = 0; i < 4; ++i) {
          v4f f = *(const v4f*)(rb + (size_t)(ci0 + i) * 3136 + w0);
#pragma unroll
          for (int j = 0; j < 4; ++j)
            dw[j] |= (((int)f[j]) & 255) << (8 * i);
        }
#pragma unroll
        for (int j = 0; j < 4; ++j)
          LB[(w0 + j) * 33 + cb] = dw[j];
      }
    }
    __syncthreads();
    for (int c = t; c < 528; c += 256) {
      int wp  = c >> 3;
      int cio = c & 7;
      int srw = wp - 1;
      v4i v = {0, 0, 0, 0};
      if (srw >= 0 && srw < 56) {
#pragma unroll
        for (int k = 0; k < 4; ++k) v[k] = LB[srw * 33 + cio * 4 + k];
      }
      *(v4i*)(dstrow + c * 16) = v;
    }
  } else {
    v4i z = {0, 0, 0, 0};
    for (int c = t; c < 528; c += 256) *(v4i*)(dstrow + c * 16) = z;
  }
}

// ---------------- w transform: OIHW fp32 -> int8 wq4 + scale ----------------
// R15 layout (kept): [kt18][chunk4][co256][16] int8. Per (kt, chunk, co-half)
// the 2KB co-run is contiguous -> the GEMM's per-thread A-DMA is one coalesced
// gload16; A-frag ds_reads are lane-contiguous (2-way aliasing = free).
__global__ __launch_bounds__(256) void xform_w(const float* __restrict__ wsrc,
                                               const int* __restrict__ Aq,
                                               const int* __restrict__ Nq,
                                               char* __restrict__ wq4,
                                               float* __restrict__ scale) {
  int idx = blockIdx.x * 256 + threadIdx.x;    // 294912
  int co = idx / 1152;
  int k  = idx - co * 1152;          // K index: g*128 + ci
  int g  = k >> 7;
  int ci = k & 127;
  int kh = g / 3;
  int kw = g - 3 * kh;
  float f = wsrc[(size_t)(co * 128 + ci) * 9 + kh * 3 + kw];
  int kt    = k >> 6;                // 0..17 (BK=64 window)
  int chunk = (k >> 4) & 3;          // 16B k-chunk within BK=64
  int col   = k & 15;
  wq4[((kt * 4 + chunk) * 256 + co) * 16 + col] = (signed char)(int)f;
  if (idx < 256) {
    scale[idx] = (float)Aq[idx] * exp2f(-(float)Nq[idx]);   // exact: A < 2^15
  }
}

// ---------------- GEMM: C[co][n,h,w] = sum_k wq[co][k] * xt[...] ----------------
// R17 = R16 (session best, 187.9us total) with the window sync count HALVED.
//   R16 window: {barrier(WAR); issue DMA(kt+1); vmcnt(3); barrier(RAW);
//   reads+MFMA} = 37 sync events/block. The WAR barrier exists only because
//   the DMA issue preceded it. Moving the issue AFTER the barrier removes the
//   race by construction: every wave's ds_reads of buf^1 drain before its own
//   MFMAs (hw waitcnt discipline), which precede barrier kt in program order;
//   the buf^1 overwrite is issued strictly after barrier kt. New window:
//   {vmcnt(0) [drains DMA(kt), issued a FULL window (~4000cy) ago -> free];
//   barrier; issue DMA(kt+1); reads + 16 MFMA} = 18 barriers + 18 free waits.
//   DMA(kt+1) stays in flight across the whole compute phase (never drained
//   fresh). Everything else byte-identical to R16 (tile/layout/epilogue/grid).
// 8 waves: wm = wv&1 (64-co strip), wn = wv>>1 (64-sp strip, = dh row).
// LDS: As[2][8192] ([chunk4][co128][16]) + Bs[2][16384] = 49152 -> 2 blk/CU.
// __launch_bounds__(512,4): VGPR cap 128 (R16-verified: no spill).
// Grid 896 = 8 XCD x 112, mt in LSB so co-halves of one tile pair per XCD.
__global__ __launch_bounds__(512, 4) void qconv_gemm(
    const char* __restrict__ xt, const char* __restrict__ wq4,
    const float* __restrict__ bias, const float* __restrict__ scale,
    const int* __restrict__ pmin, const int* __restrict__ pmax,
    float* __restrict__ out) {
  __shared__ __align__(16) char As[2][8192];   // [chunk4][co128][16]
  __shared__ __align__(16) char Bs[2][16384];  // [sp256][slot4][16], slot=ck^(sp&3)

  int bid = blockIdx.x;        // 896 = 8 XCD x 112
  int xcd = bid & 7;
  int gq  = xcd * 112 + (bid >> 3);   // 0..895, contiguous run per XCD
  int mt  = gq & 1;
  int nt  = gq >> 1;           // 0..447
  int n   = nt / 14;
  int ht  = nt - n * 14;
  int h0  = ht * 4;            // 4 output rows per block
  int m0  = mt * 128;

  int t  = threadIdx.x;        // 0..511
  int wv = t >> 6;             // 0..7
  int ln = t & 63;
  int quad = ln >> 4;
  int l16  = ln & 15;
  int wm = wv & 1, wn = wv >> 1;   // wn 0..3 = dh row

  const char* xb = xt + (size_t)n * XT_N_STRIDE + (size_t)h0 * XT_H_STRIDE;

  // A DMA source (kt-invariant tail): thread t stages dest byte t*16 of the
  // 8KB panel [chunk=t>>7][co=t&127]; src run is 2KB-contiguous.
  const int asrc_off = (t >> 7) * 4096 + mt * 2048 + (t & 127) * 16;
  // B DMA source voffsets (kt-invariant): pass p slot s = t + p*512;
  // sp = s>>2 (dh = sp>>6, w = sp&63), stored slot s&3 holds ck = (s&3)^(sp&3).
  int boffv[2];
#pragma unroll
  for (int p = 0; p < 2; ++p) {
    int s  = t + p * 512;
    int sp = s >> 2;
    boffv[p] = (sp >> 6) * XT_H_STRIDE + (sp & 63) * 128 + (((s & 3) ^ (sp & 3)) << 4);
  }
  // frag-read offsets (R12/R16-validated mappings)
  const int aoff = quad * 2048 + (wm * 64 + l16) * 16;                 // + i*256
  const int boff = (wn * 64 + l16) * 64 + ((quad ^ (l16 & 3)) << 4);   // + j*1024

  // ---- prologue: DMA kt=0 into buf 0 (drained by window 0's vmcnt) ----
  gload16(wq4 + asrc_off,     As[0] + wv * 1024);
  gload16(xb + boffv[0],      Bs[0] + wv * 1024);
  gload16(xb + boffv[1],      Bs[0] + 8192 + wv * 1024);

  v4i acc[4][4];
#pragma unroll
  for (int i = 0; i < 4; ++i)
#pragma unroll
    for (int j = 0; j < 4; ++j) {
      v4i z = {0, 0, 0, 0};
      acc[i][j] = z;
    }

#pragma unroll
  for (int kt = 0; kt < 18; ++kt) {
    const int buf = kt & 1;

    // drain DMA(kt) (issued a full window ago -> free); collective visibility.
    asm volatile("s_waitcnt vmcnt(0)" ::: "memory");
    asm volatile("s_barrier" ::: "memory");

    // issue DMA(kt+1) into buf^1 -- AFTER the barrier, so no wave can still
    // be reading buf^1 (its reads drained before its MFMAs, pre-barrier).
    if (kt < 17) {
      const int kn  = kt + 1;
      const int gn  = kn >> 1;
      const int pn  = kn & 1;
      const int khn = gn / 3;
      const int kwn = gn - 3 * khn;
      const int koff = khn * XT_H_STRIDE + kwn * 128 + pn * 64;  // uniform
      gload16(wq4 + kn * 16384 + asrc_off, As[buf ^ 1] + wv * 1024);
      gload16(xb + koff + boffv[0],        Bs[buf ^ 1] + wv * 1024);
      gload16(xb + koff + boffv[1],        Bs[buf ^ 1] + 8192 + wv * 1024);
    }

    // frag reads: plain C++ -> compiler emits fine-grained lgkmcnt (m97).
    v4i a[4], b[4];
#pragma unroll
    for (int i = 0; i < 4; ++i)
      a[i] = *(const v4i*)(As[buf] + aoff + i * 256);
#pragma unroll
    for (int j = 0; j < 4; ++j)
      b[j] = *(const v4i*)(Bs[buf] + boff + j * 1024);
#pragma unroll
    for (int i = 0; i < 4; ++i)
#pragma unroll
      for (int j = 0; j < 4; ++j)
        acc[i][j] = __builtin_amdgcn_mfma_i32_16x16x64_i8(a[i], b[j], acc[i][j], 0, 0, 0);
  }

  // epilogue (R12/R16-validated): co = m0 + wm*64 + i*16 + quad*4 + r ;
  // spatial sl = wn*64 + j*16 + l16 -> w = j*16+l16 (<64), dh = wn
  float mn = (float)pmin[0];
  float mx = (float)pmax[0];
#pragma unroll
  for (int i = 0; i < 4; ++i) {
    int co_b = m0 + wm * 64 + i * 16 + quad * 4;
    v4f bs4 = *(const v4f*)(bias + co_b);
    v4f sc4 = *(const v4f*)(scale + co_b);
#pragma unroll
    for (int r = 0; r < 4; ++r) {
      int co = co_b + r;
      float bs = bs4[r];
      float sc = sc4[r];
      size_t obase = (((size_t)n * 256 + co) * 56 + (h0 + wn)) * 56;
#pragma unroll
      for (int j = 0; j < 4; ++j) {
        int w = j * 16 + l16;
        if (w < 56) {
          float f = (float)acc[i][j][r] + bs;
          f = rintf(f * sc);                 // half-to-even, matches np.round
          f = fminf(fmaxf(f, mn), mx);
          out[obase + w] = f;
        }
      }
    }
  }
}

extern "C" void kernel_launch(void* const* d_in, const int* in_sizes, int n_in,
                              void* d_out, int out_size, void* d_ws, size_t ws_size,
                              hipStream_t stream) {
  const float* x  = (const float*)d_in[0];
  const float* w  = (const float*)d_in[1];
  const float* b  = (const float*)d_in[2];
  const int*   Aq = (const int*)d_in[3];
  const int*   Nq = (const int*)d_in[4];
  const int*   mn = (const int*)d_in[5];
  const int*   mx = (const int*)d_in[6];
  float* out = (float*)d_out;

  char*  xt    = (char*)d_ws;                  // 15,679,488 B
  char*  wq4   = xt + XT_BYTES;                // 294,912 B (kt/chunk/co256 layout)
  float* scale = (float*)(wq4 + WQ_BYTES);     // 1 KiB

  hipLaunchKernelGGL(xform_x, dim3(32 * 58), dim3(256), 0, stream, x, xt);
  hipLaunchKernelGGL(xform_w, dim3(1152), dim3(256), 0, stream, w, Aq, Nq, wq4, scale);
  hipLaunchKernelGGL(qconv_gemm, dim3(896), dim3(512), 0, stream,
                     xt, wq4, b, scale, mn, mx, out);
}

// Round 15
// 186.846 us; speedup vs baseline: 1.0231x; 1.0231x over previous
//
#include <hip/hip_runtime.h>
#include <stdint.h>

typedef int   v4i __attribute__((ext_vector_type(4)));
typedef float v4f __attribute__((ext_vector_type(4)));

// xt layout: [n][hp=58][wp=66][ci=128] int8, zero-padded (hp-1,wp-1 are src coords)
#define XT_H_STRIDE (66*128)          // 8448
#define XT_N_STRIDE (58*66*128)       // 489984
#define XT_BYTES    (32*58*66*128)    // 15,679,488
#define WQ_BYTES    (256*1152)        // 294,912

__device__ __forceinline__ void gload16(const void* g, void* l) {
  __builtin_amdgcn_global_load_lds(
      (const __attribute__((address_space(1))) void*)g,
      (__attribute__((address_space(3))) void*)l, 16, 0, 0);
}

// ---------------- x transform: fp32 NCHW -> int8 [n][hp][wp][ci] ----------------
// Coalesced both sides via LDS transpose. Unchanged (proven, HBM roofline).
__global__ __launch_bounds__(256) void xform_x(const float* __restrict__ x,
                                               char* __restrict__ xt) {
  __shared__ int LB[56 * 33];          // [w][32 ci-dwords + 1 pad]
  int bid = blockIdx.x;                // 32*58
  int n  = bid / 58;
  int hp = bid - n * 58;
  int t  = threadIdx.x;
  int srch = hp - 1;
  bool rowok = (srch >= 0) && (srch < 56);
  char* dstrow = xt + (size_t)n * XT_N_STRIDE + (size_t)hp * XT_H_STRIDE;

  if (rowok) {
    const float* rb = x + ((size_t)(n * 128) * 56 + srch) * 56;   // + ci*3136 + w
#pragma unroll
    for (int u0 = 0; u0 < 2; ++u0) {
      int u  = t + u0 * 256;
      int wb = u & 15;
      int cb = u >> 4;
      int w0 = wb * 4, ci0 = cb * 4;
      if (w0 < 56) {
        int dw[4] = {0, 0, 0, 0};
#pragma unroll
        for (int i = 0; i < 4; ++i) {
          v4f f = *(const v4f*)(rb + (size_t)(ci0 + i) * 3136 + w0);
#pragma unroll
          for (int j = 0; j < 4; ++j)
            dw[j] |= (((int)f[j]) & 255) << (8 * i);
        }
#pragma unroll
        for (int j = 0; j < 4; ++j)
          LB[(w0 + j) * 33 + cb] = dw[j];
      }
    }
    __syncthreads();
    for (int c = t; c < 528; c += 256) {
      int wp  = c >> 3;
      int cio = c & 7;
      int srw = wp - 1;
      v4i v = {0, 0, 0, 0};
      if (srw >= 0 && srw < 56) {
#pragma unroll
        for (int k = 0; k < 4; ++k) v[k] = LB[srw * 33 + cio * 4 + k];
      }
      *(v4i*)(dstrow + c * 16) = v;
    }
  } else {
    v4i z = {0, 0, 0, 0};
    for (int c = t; c < 528; c += 256) *(v4i*)(dstrow + c * 16) = z;
  }
}

// ---------------- w transform: OIHW fp32 -> int8 wq4 + scale ----------------
// Layout: [kt18][chunk4][co256][16] int8. Per (kt, chunk, co-half) the 2KB
// co-run is contiguous -> the GEMM's per-thread A-DMA is one coalesced
// gload16; A-frag ds_reads are lane-contiguous (2-way aliasing = free).
__global__ __launch_bounds__(256) void xform_w(const float* __restrict__ wsrc,
                                               const int* __restrict__ Aq,
                                               const int* __restrict__ Nq,
                                               char* __restrict__ wq4,
                                               float* __restrict__ scale) {
  int idx = blockIdx.x * 256 + threadIdx.x;    // 294912
  int co = idx / 1152;
  int k  = idx - co * 1152;          // K index: g*128 + ci
  int g  = k >> 7;
  int ci = k & 127;
  int kh = g / 3;
  int kw = g - 3 * kh;
  float f = wsrc[(size_t)(co * 128 + ci) * 9 + kh * 3 + kw];
  int kt    = k >> 6;                // 0..17 (BK=64 window)
  int chunk = (k >> 4) & 3;          // 16B k-chunk within BK=64
  int col   = k & 15;
  wq4[((kt * 4 + chunk) * 256 + co) * 16 + col] = (signed char)(int)f;
  if (idx < 256) {
    scale[idx] = (float)Aq[idx] * exp2f(-(float)Nq[idx]);   // exact: A < 2^15
  }
}

// ---------------- GEMM: C[co][n,h,w] = sum_k wq[co][k] * xt[...] ----------------
// R18 = R16 verbatim (session best, 187.9us; R17's sync-halving was a null).
// FINAL form. Cycle accounting at R16's counters closes: per CU-window
// 2095 cy measured vs LDS pipe 128 ds_read_b128 x 12cy + 48KB DMA-write
// ~= 1920 cy (~92% busy) -> the LDS pipe is the binding resource, and the
// 2co x 4sp wave split minimizes LDS bytes (64/p + 128/q KB, p*q=8 => p=2,q=4).
// Escapes via L1/global operands measured worse 3x (R5/R6 60-63, R13 105,
// R14 63). Occupancy >16 waves/CU impossible (64-VGPR acc; R15 spill).
// Window: {barrier(WAR); issue DMA(kt+1); vmcnt(3); barrier(RAW); plain
// frag reads (compiler lgkmcnt) + 16 MFMA}. No setprio/sched_barrier games.
// 8 waves: wm = wv&1 (64-co strip), wn = wv>>1 (64-sp strip, = dh row).
// LDS: As[2][8192] ([chunk4][co128][16]) + Bs[2][16384] = 49152 -> 2 blk/CU.
// __launch_bounds__(512,4): VGPR cap 128 (R16-verified: no spill).
// Grid 896 = 8 XCD x 112, mt in LSB so co-halves of one tile pair per XCD.
__global__ __launch_bounds__(512, 4) void qconv_gemm(
    const char* __restrict__ xt, const char* __restrict__ wq4,
    const float* __restrict__ bias, const float* __restrict__ scale,
    const int* __restrict__ pmin, const int* __restrict__ pmax,
    float* __restrict__ out) {
  __shared__ __align__(16) char As[2][8192];   // [chunk4][co128][16]
  __shared__ __align__(16) char Bs[2][16384];  // [sp256][slot4][16], slot=ck^(sp&3)

  int bid = blockIdx.x;        // 896 = 8 XCD x 112
  int xcd = bid & 7;
  int gq  = xcd * 112 + (bid >> 3);   // 0..895, contiguous run per XCD
  int mt  = gq & 1;
  int nt  = gq >> 1;           // 0..447
  int n   = nt / 14;
  int ht  = nt - n * 14;
  int h0  = ht * 4;            // 4 output rows per block
  int m0  = mt * 128;

  int t  = threadIdx.x;        // 0..511
  int wv = t >> 6;             // 0..7
  int ln = t & 63;
  int quad = ln >> 4;
  int l16  = ln & 15;
  int wm = wv & 1, wn = wv >> 1;   // wn 0..3 = dh row

  const char* xb = xt + (size_t)n * XT_N_STRIDE + (size_t)h0 * XT_H_STRIDE;

  // A DMA source (kt-invariant tail): thread t stages dest byte t*16 of the
  // 8KB panel [chunk=t>>7][co=t&127]; src run is 2KB-contiguous.
  const int asrc_off = (t >> 7) * 4096 + mt * 2048 + (t & 127) * 16;
  // B DMA source voffsets (kt-invariant): pass p slot s = t + p*512;
  // sp = s>>2 (dh = sp>>6, w = sp&63), stored slot s&3 holds ck = (s&3)^(sp&3).
  int boffv[2];
#pragma unroll
  for (int p = 0; p < 2; ++p) {
    int s  = t + p * 512;
    int sp = s >> 2;
    boffv[p] = (sp >> 6) * XT_H_STRIDE + (sp & 63) * 128 + (((s & 3) ^ (sp & 3)) << 4);
  }
  // frag-read offsets (R12/R16-validated mappings)
  const int aoff = quad * 2048 + (wm * 64 + l16) * 16;                 // + i*256
  const int boff = (wn * 64 + l16) * 64 + ((quad ^ (l16 & 3)) << 4);   // + j*1024

  // ---- prologue: DMA kt=0 into buf 0 ----
  gload16(wq4 + asrc_off,     As[0] + wv * 1024);
  gload16(xb + boffv[0],      Bs[0] + wv * 1024);
  gload16(xb + boffv[1],      Bs[0] + 8192 + wv * 1024);
  asm volatile("s_waitcnt vmcnt(0)" ::: "memory");
  asm volatile("s_barrier" ::: "memory");

  v4i acc[4][4];
#pragma unroll
  for (int i = 0; i < 4; ++i)
#pragma unroll
    for (int j = 0; j < 4; ++j) {
      v4i z = {0, 0, 0, 0};
      acc[i][j] = z;
    }

#pragma unroll
  for (int kt = 0; kt < 18; ++kt) {
    const int buf = kt & 1;

    // all waves finished reading buf^1 (in kt-1) -> safe to DMA-overwrite it
    asm volatile("s_barrier" ::: "memory");
    if (kt < 17) {
      const int kn  = kt + 1;
      const int gn  = kn >> 1;
      const int pn  = kn & 1;
      const int khn = gn / 3;
      const int kwn = gn - 3 * khn;
      const int koff = khn * XT_H_STRIDE + kwn * 128 + pn * 64;  // uniform
      gload16(wq4 + kn * 16384 + asrc_off, As[buf ^ 1] + wv * 1024);
      gload16(xb + koff + boffv[0],        Bs[buf ^ 1] + wv * 1024);
      gload16(xb + koff + boffv[1],        Bs[buf ^ 1] + 8192 + wv * 1024);
      asm volatile("s_waitcnt vmcnt(3)" ::: "memory");  // current buf's 3 landed
    } else {
      asm volatile("s_waitcnt vmcnt(0)" ::: "memory");
    }
    asm volatile("s_barrier" ::: "memory");             // cross-wave: buf ready

    // frag reads: plain C++ -> compiler emits fine-grained lgkmcnt (m97).
    v4i a[4], b[4];
#pragma unroll
    for (int i = 0; i < 4; ++i)
      a[i] = *(const v4i*)(As[buf] + aoff + i * 256);
#pragma unroll
    for (int j = 0; j < 4; ++j)
      b[j] = *(const v4i*)(Bs[buf] + boff + j * 1024);
#pragma unroll
    for (int i = 0; i < 4; ++i)
#pragma unroll
      for (int j = 0; j < 4; ++j)
        acc[i][j] = __builtin_amdgcn_mfma_i32_16x16x64_i8(a[i], b[j], acc[i][j], 0, 0, 0);
  }

  // epilogue (R12/R16-validated): co = m0 + wm*64 + i*16 + quad*4 + r ;
  // spatial sl = wn*64 + j*16 + l16 -> w = j*16+l16 (<64), dh = wn
  float mn = (float)pmin[0];
  float mx = (float)pmax[0];
#pragma unroll
  for (int i = 0; i < 4; ++i) {
    int co_b = m0 + wm * 64 + i * 16 + quad * 4;
    v4f bs4 = *(const v4f*)(bias + co_b);
    v4f sc4 = *(const v4f*)(scale + co_b);
#pragma unroll
    for (int r = 0; r < 4; ++r) {
      int co = co_b + r;
      float bs = bs4[r];
      float sc = sc4[r];
      size_t obase = (((size_t)n * 256 + co) * 56 + (h0 + wn)) * 56;
#pragma unroll
      for (int j = 0; j < 4; ++j) {
        int w = j * 16 + l16;
        if (w < 56) {
          float f = (float)acc[i][j][r] + bs;
          f = rintf(f * sc);                 // half-to-even, matches np.round
          f = fminf(fmaxf(f, mn), mx);
          out[obase + w] = f;
        }
      }
    }
  }
}

extern "C" void kernel_launch(void* const* d_in, const int* in_sizes, int n_in,
                              void* d_out, int out_size, void* d_ws, size_t ws_size,
                              hipStream_t stream) {
  const float* x  = (const float*)d_in[0];
  const float* w  = (const float*)d_in[1];
  const float* b  = (const float*)d_in[2];
  const int*   Aq = (const int*)d_in[3];
  const int*   Nq = (const int*)d_in[4];
  const int*   mn = (const int*)d_in[5];
  const int*   mx = (const int*)d_in[6];
  float* out = (float*)d_out;

  char*  xt    = (char*)d_ws;                  // 15,679,488 B
  char*  wq4   = xt + XT_BYTES;                // 294,912 B (kt/chunk/co256 layout)
  float* scale = (float*)(wq4 + WQ_BYTES);     // 1 KiB

  hipLaunchKernelGGL(xform_x, dim3(32 * 58), dim3(256), 0, stream, x, xt);
  hipLaunchKernelGGL(xform_w, dim3(1152), dim3(256), 0, stream, w, Aq, Nq, wq4, scale);
  hipLaunchKernelGGL(qconv_gemm, dim3(896), dim3(512), 0, stream,
                     xt, wq4, b, scale, mn, mx, out);
}